// Round 18
// baseline (234.140 us; speedup 1.0000x reference)
//
#include <hip/hip_runtime.h>
#include <hip/hip_bf16.h>
#include <stdint.h>
#include <stddef.h>

typedef __attribute__((ext_vector_type(8))) short short8v;   // 8 bf16 = 4 VGPR
typedef __attribute__((ext_vector_type(4))) float f32x4;
typedef unsigned short us;

__device__ __forceinline__ float bf2f(unsigned short u) {
    return __uint_as_float(((unsigned int)u) << 16);
}
__device__ __forceinline__ unsigned short f2bf(float f) {
    unsigned int x = __float_as_uint(f);
    x += 0x7fffu + ((x >> 16) & 1u);   // RNE
    return (unsigned short)(x >> 16);
}
__device__ __forceinline__ unsigned int cvtpk(float lo, float hi) {
    unsigned int r;
    asm("v_cvt_pk_bf16_f32 %0, %1, %2" : "=v"(r) : "v"(lo), "v"(hi));
    return r;
}

#define NTOK 8192
#define DM   1024
#define NPROJ 3072     // q512 | k512 | v1024 | g1024
#define SEQ  4096
#define NCHUNK 64
#define SCQ 0.08838834764831845f   // 128^-0.5

#define GLDS16(g, l) __builtin_amdgcn_global_load_lds( \
    (const __attribute__((address_space(1))) void*)(g), \
    (__attribute__((address_space(3))) void*)(l), 16, 0, 0)

__device__ __forceinline__ void bar_lgkm() {
    asm volatile("s_waitcnt lgkmcnt(0)" ::: "memory");
    __builtin_amdgcn_s_barrier();
    __builtin_amdgcn_sched_barrier(0);
}

// ---- swizzles (element offsets, 2B elems) ----
__device__ __forceinline__ int sw16(int row, int k) {
    int u = k >> 3;
    int us_ = (u & 8) | ((u ^ row) & 7);
    return row * 128 + us_ * 8 + (k & 7);
}
__device__ __forceinline__ int sw8(int row, int k) {
    int u = k >> 3;
    int us_ = (u ^ row) & 7;
    return row * 64 + us_ * 8 + (k & 7);
}
__device__ __forceinline__ int sw128(int row, int k) {   // [R][128] tile
    int u = k >> 3;
    return row * 128 + ((u ^ row) & 15) * 8 + (k & 7);
}
__device__ __forceinline__ int sw64(int row, int k) {    // [R][64] tile
    int u = k >> 3;
    return row * 64 + ((u ^ row) & 7) * 8 + (k & 7);
}
__device__ __forceinline__ int sw64b(int row, int k) {   // bank-spread scatter variant
    int u = k >> 3;
    return row * 64 + ((u ^ row ^ (row >> 3)) & 7) * 8 + (k & 7);
}
__device__ __forceinline__ int swU(int t, int j) {       // Ubuf [t][256]
    int jj = j & 127, u = jj >> 3;
    int us_ = (u & 8) | ((u ^ t) & 7);
    return t * 256 + (j >> 7) * 128 + us_ * 8 + (jj & 7);
}
__device__ __forceinline__ int swU128(int t, int jj) {
    int u = jj >> 3;
    int us_ = (u & 8) | ((u ^ t) & 7);
    return t * 128 + us_ * 8 + (jj & 7);
}

// ---------------- PREP: x->bf16 image + beta (blocks 0..4095), W transposes (4096..5119) ----
__global__ __launch_bounds__(256) void prep(
    const float* __restrict__ x, us* __restrict__ xb,
    const float* __restrict__ Wb, float* __restrict__ beta,
    const float* __restrict__ Wq, const float* __restrict__ Wk,
    const float* __restrict__ Wv, const float* __restrict__ Wg,
    const float* __restrict__ Wo, us* __restrict__ WT, us* __restrict__ WoT)
{
    __shared__ float smem[64 * 65];   // 16640 B: transpose tile / beta partials
    int tid = threadIdx.x;
    int bid = blockIdx.x;

    if (bid < 4096) {
        int i = bid * 256 + tid;
        int tok = i >> 7;
        int kb = (i >> 3) & 15;
        int u = i & 7;
        int ko = kb * 64 + ((u ^ (tok & 7)) * 8);
        const float4* src = (const float4*)(x + (size_t)tok * 1024 + ko);
        float4 v0 = src[0], v1 = src[1];
        uint4 o;
        o.x = cvtpk(v0.x, v0.y); o.y = cvtpk(v0.z, v0.w);
        o.z = cvtpk(v1.x, v1.y); o.w = cvtpk(v1.z, v1.w);
        *(uint4*)(xb + (size_t)i * 8) = o;
        const float4* wbv = (const float4*)Wb;
        float xs[8] = {v0.x, v0.y, v0.z, v0.w, v1.x, v1.y, v1.z, v1.w};
        float4 s = {0.f, 0.f, 0.f, 0.f};
        #pragma unroll
        for (int e = 0; e < 8; e++) {
            float4 w = wbv[ko + e];
            s.x += xs[e] * w.x; s.y += xs[e] * w.y;
            s.z += xs[e] * w.z; s.w += xs[e] * w.w;
        }
        *(float4*)&smem[tid * 4] = s;
        __syncthreads();
        if (tid < 8) {
            int tp = tid >> 2, h = tid & 3;
            float acc = 0.f;
            for (int j = 0; j < 128; j++) acc += smem[(tp * 128 + j) * 4 + h];
            beta[(size_t)(bid * 2 + tp) * 4 + h] = 1.f / (1.f + __expf(-acc));
        }
        return;
    }

    int lb = bid - 4096;
    const float* srcw; us* dst; int N;
    if (lb < 128)      { srcw = Wq; dst = WT;                    N = 512;  }
    else if (lb < 256) { srcw = Wk; dst = WT + (size_t)512 * DM;  N = 512;  lb -= 128; }
    else if (lb < 512) { srcw = Wv; dst = WT + (size_t)1024 * DM; N = 1024; lb -= 256; }
    else if (lb < 768) { srcw = Wg; dst = WT + (size_t)2048 * DM; N = 1024; lb -= 512; }
    else               { srcw = Wo; dst = WoT;                   N = 1024; lb -= 768; }
    int nbx = N >> 6;
    int n0 = (lb % nbx) * 64, k0 = (lb / nbx) * 64;
    float (*tl)[65] = (float(*)[65])smem;
    int tr = tid >> 6, tc = tid & 63;
    #pragma unroll
    for (int i2 = 0; i2 < 16; i2++) {
        int kk = 4 * i2 + tr;
        tl[kk][tc] = srcw[(size_t)(k0 + kk) * N + n0 + tc];
    }
    __syncthreads();
    int n = tid >> 2, seg = (tid & 3) * 16;
    short8v a, b;
    #pragma unroll
    for (int e = 0; e < 8; e++) {
        a[e] = (short)f2bf(tl[seg + e][n]);
        b[e] = (short)f2bf(tl[seg + 8 + e][n]);
    }
    int n_ = n0 + n;
    int o1 = (tid & 3) * 2, o2_ = o1 + 1;
    us* d = dst + (size_t)n_ * DM + k0;
    *(short8v*)(d + (o1 ^ (n_ & 7)) * 8) = a;
    *(short8v*)(d + (o2_ ^ (n_ & 7)) * 8) = b;
}

// ---------------- bf16 MFMA GEMM, BK=64, image-swizzled, T3-lite 2-phase dbuf -------
template<int OUT_F32>
__global__ __launch_bounds__(256) void gemm_bt(
    const us* __restrict__ A, const us* __restrict__ BT,
    void* __restrict__ C, int M, int N, int K)
{
    __shared__ us As[2][128 * 64];
    __shared__ us Bs[2][128 * 64];
    int tid = threadIdx.x;
    int wave = tid >> 6, lane = tid & 63;
    int wr = (wave >> 1) * 64, wc = (wave & 1) * 64;
    int fr = lane & 15, fq = lane >> 4;
    int nbx = gridDim.x, nwg = nbx * gridDim.y;
    int wg = blockIdx.y * nbx + blockIdx.x;
    int cpx = nwg >> 3;
    wg = (wg & 7) * cpx + (wg >> 3);
    int m0 = (wg % nbx) * 128, n0 = (wg / nbx) * 128;

    f32x4 acc[4][4];
    #pragma unroll
    for (int i = 0; i < 4; i++)
        #pragma unroll
        for (int j = 0; j < 4; j++) acc[i][j] = (f32x4){0.f, 0.f, 0.f, 0.f};

    int rl = lane >> 3, ul = lane & 7;

    auto issue = [&](int k0, int bufi) {
        #pragma unroll
        for (int i = 0; i < 4; i++) {
            int row = wave * 32 + i * 8 + rl;
            GLDS16(&A[(size_t)(m0 + row) * K + k0 + ul * 8], &As[bufi][(wave * 32 + i * 8) * 64]);
            GLDS16(&BT[(size_t)(n0 + row) * K + k0 + ul * 8], &Bs[bufi][(wave * 32 + i * 8) * 64]);
        }
    };

    int NT = K >> 6;
    issue(0, 0);
    if (NT > 1) issue(64, 1);

    for (int t = 0; t < NT; t++) {
        // gate tile t's 8 loads (t+1's stay in flight); never drain mid-loop
        if (t + 1 < NT) asm volatile("s_waitcnt vmcnt(8)" ::: "memory");
        else            asm volatile("s_waitcnt vmcnt(0)" ::: "memory");
        __builtin_amdgcn_sched_barrier(0);
        __builtin_amdgcn_s_barrier();
        __builtin_amdgcn_sched_barrier(0);
        const us* as = As[t & 1];
        const us* bs = Bs[t & 1];
        #pragma unroll
        for (int kk = 0; kk < 2; kk++) {
            short8v a[4], b[4];
            #pragma unroll
            for (int i = 0; i < 4; i++) {
                int ra = wr + i * 16 + fr;
                a[i] = *(const short8v*)&as[ra * 64 + ((4 * kk + fq) ^ (ra & 7)) * 8];
                int rb = wc + i * 16 + fr;
                b[i] = *(const short8v*)&bs[rb * 64 + ((4 * kk + fq) ^ (rb & 7)) * 8];
            }
            #pragma unroll
            for (int i = 0; i < 4; i++)
                #pragma unroll
                for (int j = 0; j < 4; j++)
                    acc[i][j] = __builtin_amdgcn_mfma_f32_16x16x32_bf16(a[i], b[j], acc[i][j], 0, 0, 0);
        }
        bar_lgkm();   // all reads of this buffer done before refill
        if (t + 2 < NT) issue((t + 2) * 64, t & 1);
    }

    #pragma unroll
    for (int i = 0; i < 4; i++)
        #pragma unroll
        for (int j = 0; j < 4; j++)
            #pragma unroll
            for (int t = 0; t < 4; t++) {
                int row = m0 + wr + i * 16 + fq * 4 + t;
                int col = n0 + wc + j * 16 + fr;
                float val = acc[i][j][t];
                if (OUT_F32) ((float*)C)[(size_t)row * N + col] = val;
                else ((us*)C)[(size_t)row * N + col] = f2bf(val);
            }
}

// ---------------- per-chunk precompute (NO Q dependency; writes Kbuf image) -------
__global__ __launch_bounds__(256) void chunk_pre(
    const us* __restrict__ QKVG, const float* __restrict__ beta,
    us* __restrict__ Wbuf, us* __restrict__ Ubuf,
    us* __restrict__ Kbuf, us* __restrict__ KTbuf)
{
    __shared__ us Ks[8192];
    __shared__ us KTs[8192];
    __shared__ us VT[8192];
    __shared__ us Tb[4096];
    __shared__ float Af[64][64];
    __shared__ float betas[64];

    int c = blockIdx.x, bh = blockIdx.y;
    int b = bh >> 2, h = bh & 3;
    int tid = threadIdx.x;
    int wv = tid >> 6, ln = tid & 63;
    int fr = ln & 15, fq = ln >> 4;
    int tok0 = b * SEQ + c * 64;
    size_t cb = (size_t)bh * NCHUNK + c;

    #pragma unroll
    for (int r = 0; r < 4; r++) {
        int idx = tid + 256 * r;
        int t = idx >> 4, u = idx & 15;
        short8v kv = *(const short8v*)(QKVG + (size_t)(tok0 + t) * NPROJ + 512 + h * 128 + u * 8);
        *(short8v*)(Ks + sw16(t, u * 8)) = kv;
    }
    if (tid < 64) betas[tid] = beta[(size_t)(tok0 + tid) * 4 + h];
    __syncthreads();

    {   // L2-normalize K rows
        int t = tid >> 2, p = tid & 3;
        short8v v[4];
        float ss = 0.f;
        #pragma unroll
        for (int uu = 0; uu < 4; uu++) {
            v[uu] = *(const short8v*)(Ks + sw16(t, (p * 4 + uu) * 8));
            #pragma unroll
            for (int e = 0; e < 8; e++) {
                float f = bf2f((unsigned short)v[uu][e]);
                ss += f * f;
            }
        }
        ss += __shfl_xor(ss, 1);
        ss += __shfl_xor(ss, 2);
        float rn = rsqrtf(ss + 1e-12f);
        #pragma unroll
        for (int uu = 0; uu < 4; uu++) {
            short8v o;
            #pragma unroll
            for (int e = 0; e < 8; e++)
                o[e] = (short)f2bf(bf2f((unsigned short)v[uu][e]) * rn);
            *(short8v*)(Ks + sw16(t, (p * 4 + uu) * 8)) = o;
        }
    }
    __syncthreads();

    {   // A = strict_tril(beta_t K K^T)
        f32x4 aacc[4];
        #pragma unroll
        for (int jt = 0; jt < 4; jt++) aacc[jt] = (f32x4){0.f, 0.f, 0.f, 0.f};
        #pragma unroll
        for (int ks = 0; ks < 4; ks++) {
            short8v ak = *(const short8v*)(Ks + sw16(16 * wv + fr, 32 * ks + 8 * fq));
            #pragma unroll
            for (int jt = 0; jt < 4; jt++) {
                short8v bk = *(const short8v*)(Ks + sw16(16 * jt + fr, 32 * ks + 8 * fq));
                aacc[jt] = __builtin_amdgcn_mfma_f32_16x16x32_bf16(ak, bk, aacc[jt], 0, 0, 0);
            }
        }
        #pragma unroll
        for (int jt = 0; jt < 4; jt++)
            #pragma unroll
            for (int r = 0; r < 4; r++) {
                int t = 16 * wv + 4 * fq + r, s = 16 * jt + fr;
                if (s < t) Af[t][s] = betas[t] * aacc[jt][r];
            }
    }
    __syncthreads();

    if (wv == 0) {
        // blocked right-looking forward substitution
        int cc = ln;
        for (int tb = 0; tb < 8; tb++) {
            int base = tb * 8;
            float xs[8];
            #pragma unroll
            for (int i = 0; i < 8; i++) {
                int t = base + i;
                float v = Af[t][cc];
                #pragma unroll
                for (int s = 0; s < i; s++)
                    v += Af[t][base + s] * xs[s];
                float xt = (cc < t) ? -v : 0.f;
                xs[i] = xt;
                if (cc < t) Af[t][cc] = xt;
            }
            for (int r = base + 8; r < 64; r += 2) {
                float u0 = 0.f, u1 = 0.f;
                #pragma unroll
                for (int s = 0; s < 8; s++) {
                    float a0 = Af[r][base + s];
                    float a1 = Af[r + 1][base + s];
                    u0 += a0 * xs[s];
                    u1 += a1 * xs[s];
                }
                Af[r][cc] += u0;
                Af[r + 1][cc] += u1;
            }
        }
    } else {
        int q = tid - 64;
        for (int g = q; g < 1024; g += 192) {
            int t = g >> 4, u = g & 15;
            short8v kv = *(const short8v*)(Ks + sw16(t, u * 8));
            #pragma unroll
            for (int e = 0; e < 8; e++)
                KTs[sw64b(u * 8 + e, t)] = (unsigned short)kv[e];
        }
        for (int g = q; g < 1024; g += 192) {
            int t = g >> 4, jg = g & 15;
            short8v vv = *(const short8v*)(QKVG + (size_t)(tok0 + t) * NPROJ + 1024 + h * 256 + jg * 8);
            #pragma unroll
            for (int e = 0; e < 8; e++)
                VT[sw64b(jg * 8 + e, t)] = (unsigned short)vv[e];
        }
    }
    __syncthreads();

    {   // Kbuf image (normalized K, sw128), Tb, KTbuf image copy
        #pragma unroll
        for (int i = 0; i < 4; i++) {
            int idx = tid + 256 * i;   // 0..1023
            int t = idx >> 4, u = idx & 15;
            short8v kv = *(const short8v*)(Ks + sw16(t, u * 8));
            *(short8v*)(Kbuf + cb * 8192 + t * 128 + (size_t)(((u ^ t) & 15) * 8)) = kv;
        }
        #pragma unroll
        for (int i = 0; i < 16; i++) {
            int idx = tid + 256 * i;
            int t = idx >> 6, s = idx & 63;
            float tv = (s < t) ? Af[t][s] : (s == t ? 1.f : 0.f);
            Tb[sw8(t, s)] = f2bf(tv * betas[s]);
        }
        #pragma unroll
        for (int i = 0; i < 4; i++) {
            int idx = tid + 256 * i;
            *(short8v*)(KTbuf + cb * 8192 + (size_t)idx * 8) =
                *(const short8v*)(KTs + (size_t)idx * 8);
        }
    }
    __syncthreads();

    {   // W = -(T'K) (d-half images), U half0
        f32x4 wacc[8], uacc[8];
        #pragma unroll
        for (int jt = 0; jt < 8; jt++) {
            wacc[jt] = (f32x4){0.f, 0.f, 0.f, 0.f};
            uacc[jt] = (f32x4){0.f, 0.f, 0.f, 0.f};
        }
        #pragma unroll
        for (int ks = 0; ks < 2; ks++) {
            short8v at = *(const short8v*)(Tb + sw8(16 * wv + fr, 32 * ks + 8 * fq));
            #pragma unroll
            for (int jt = 0; jt < 8; jt++) {
                short8v bk = *(const short8v*)(KTs + sw64b(16 * jt + fr, 32 * ks + 8 * fq));
                wacc[jt] = __builtin_amdgcn_mfma_f32_16x16x32_bf16(at, bk, wacc[jt], 0, 0, 0);
                short8v bv = *(const short8v*)(VT + sw64b(16 * jt + fr, 32 * ks + 8 * fq));
                uacc[jt] = __builtin_amdgcn_mfma_f32_16x16x32_bf16(at, bv, uacc[jt], 0, 0, 0);
            }
        }
        #pragma unroll
        for (int jt = 0; jt < 8; jt++)
            #pragma unroll
            for (int r = 0; r < 4; r++) {
                int t = 16 * wv + 4 * fq + r, d = 16 * jt + fr;
                Wbuf[cb * 8192 + (d >> 6) * 4096 + sw64(t, d & 63)] = f2bf(-wacc[jt][r]);
                Ubuf[cb * 16384 + swU(t, d)] = f2bf(uacc[jt][r]);
            }
    }
    __syncthreads();

    #pragma unroll
    for (int i = 0; i < 4; i++) {   // restage V^T half1
        int g = tid + 256 * i;
        int t = g >> 4, jg = g & 15;
        short8v vv = *(const short8v*)(QKVG + (size_t)(tok0 + t) * NPROJ + 1024 + h * 256 + 128 + jg * 8);
        #pragma unroll
        for (int e = 0; e < 8; e++)
            VT[sw64b(jg * 8 + e, t)] = (unsigned short)vv[e];
    }
    __syncthreads();
    {
        f32x4 uacc[8];
        #pragma unroll
        for (int jt = 0; jt < 8; jt++) uacc[jt] = (f32x4){0.f, 0.f, 0.f, 0.f};
        #pragma unroll
        for (int ks = 0; ks < 2; ks++) {
            short8v at = *(const short8v*)(Tb + sw8(16 * wv + fr, 32 * ks + 8 * fq));
            #pragma unroll
            for (int jt = 0; jt < 8; jt++) {
                short8v bv = *(const short8v*)(VT + sw64b(16 * jt + fr, 32 * ks + 8 * fq));
                uacc[jt] = __builtin_amdgcn_mfma_f32_16x16x32_bf16(at, bv, uacc[jt], 0, 0, 0);
            }
        }
        #pragma unroll
        for (int jt = 0; jt < 8; jt++)
            #pragma unroll
            for (int r = 0; r < 4; r++) {
                int t = 16 * wv + 4 * fq + r, j = 16 * jt + fr;
                Ubuf[cb * 16384 + swU(t, 128 + j)] = f2bf(uacc[jt][r]);
            }
    }
}

// ---------------- FUSED: serial scan (blocks 0..127) + Q/G projection gemm ----------
#define SCW 0
#define SCKT 8192
#define SCU 16384
#define SCBUF 17408
#define SSTB (2 * SCBUF)
#define SDTB (2 * SCBUF + 2048)
// scan total 40960 elems = 81920 B; gemm part uses 16384 elems.

__global__ __launch_bounds__(256, 1) void fused_scan_qg(
    const us* __restrict__ xb, const us* __restrict__ WT, us* __restrict__ QKVG,
    const us* __restrict__ Wbuf, const us* __restrict__ Ubuf,
    const us* __restrict__ KTbuf, us* __restrict__ Sbuf)
{
    extern __shared__ us lds[];
    int tid = threadIdx.x;

    if (blockIdx.x < 128) {
        // ---------------- scan part ----------------
        if (tid >= 128) {   // waves 2-3: match the scan's 64 barriers, then exit
            for (int c = 0; c < NCHUNK; c++) __builtin_amdgcn_s_barrier();
            return;
        }
        int wv = tid >> 6, ln = tid & 63;
        int fr = ln & 15, fq = ln >> 4;
        int sl = blockIdx.x >> 3;
        int j0 = sl * 16;
        int bh = blockIdx.x & 7;

        short8v id0;
        #pragma unroll
        for (int e = 0; e < 8; e++)
            id0[e] = (short)((8 * fq + e == fr) ? 0x3F80 : 0);

        f32x4 sacc[4];
        #pragma unroll
        for (int i = 0; i < 4; i++) sacc[i] = (f32x4){0.f, 0.f, 0.f, 0.f};

        us* ST = lds + SSTB + wv * 1024;

        auto issue = [&](int c1) {
            size_t cb = (size_t)bh * NCHUNK + c1;
            us* dst = lds + (c1 & 1) * SCBUF;
            const us* Wc = Wbuf + cb * 8192 + wv * 4096;
            const us* Kc = KTbuf + cb * 8192 + wv * 4096;
            #pragma unroll
            for (int i = 0; i < 8; i++) {
                GLDS16(Wc + i * 512 + ln * 8, dst + SCW + wv * 4096 + i * 512);
                GLDS16(Kc + i * 512 + ln * 8, dst + SCKT + wv * 4096 + i * 512);
            }
            if (wv) {
                const us* Uc = Ubuf + cb * 16384;
                #pragma unroll
                for (int i = 0; i < 2; i++) {
                    int t = i * 32 + (ln >> 1);
                    GLDS16(Uc + swU(t, j0 + (ln & 1) * 8), dst + SCU + i * 512);
                }
            }
        };

        issue(0);

        for (int c = 0; c < NCHUNK; c++) {
            const us* ba = lds + (c & 1) * SCBUF;
            us* DTw = lds + SDTB + (c & 1) * 2048 + wv * 1024;
            const us* DTr = lds + SDTB + (c & 1) * 2048;
            size_t sb = ((size_t)bh * NCHUNK + c) * 32768 + sl * 2048 + wv * 1024;

            #pragma unroll
            for (int dt = 0; dt < 4; dt++) {
                uint2 w;
                w.x = cvtpk(sacc[dt][0], sacc[dt][1]);
                w.y = cvtpk(sacc[dt][2], sacc[dt][3]);
                int dl = 16 * dt + 4 * fq;
                int off = fr * 64 + (((dl >> 3) ^ fr) & 7) * 8 + (dl & 7);
                *(uint2*)&ST[off] = w;
                *(uint2*)(Sbuf + sb + off) = w;
            }
            if (c + 1 < NCHUNK) issue(c + 1);
            if (c + 1 < NCHUNK) {
                if (wv) asm volatile("s_waitcnt vmcnt(22)" ::: "memory");
                else    asm volatile("s_waitcnt vmcnt(20)" ::: "memory");
            } else {
                asm volatile("s_waitcnt vmcnt(4)" ::: "memory");
            }
            __builtin_amdgcn_sched_barrier(0);

            f32x4 dacc[4];
            #pragma unroll
            for (int tt = 0; tt < 4; tt++) dacc[tt] = (f32x4){0.f, 0.f, 0.f, 0.f};
            #pragma unroll
            for (int kc = 0; kc < 2; kc++) {
                short8v bs = *(const short8v*)&ST[fr * 64 + (((4 * kc + fq) ^ fr) & 7) * 8];
                #pragma unroll
                for (int tt = 0; tt < 4; tt++) {
                    short8v aw = *(const short8v*)&ba[SCW + wv * 4096 + sw64(16 * tt + fr, 32 * kc + 8 * fq)];
                    dacc[tt] = __builtin_amdgcn_mfma_f32_16x16x32_bf16(aw, bs, dacc[tt], 0, 0, 0);
                }
            }
            if (wv) {
                #pragma unroll
                for (int tt = 0; tt < 4; tt++) {
                    short8v au = *(const short8v*)&ba[SCU + (16 * tt + fr) * 16 + 8 * (fq & 1)];
                    dacc[tt] = __builtin_amdgcn_mfma_f32_16x16x32_bf16(au, id0, dacc[tt], 0, 0, 0);
                }
            }
            #pragma unroll
            for (int tt = 0; tt < 4; tt++) {
                uint2 w;
                w.x = cvtpk(dacc[tt][0], dacc[tt][1]);
                w.y = cvtpk(dacc[tt][2], dacc[tt][3]);
                int tl = 16 * tt + 4 * fq;
                *(uint2*)&DTw[fr * 64 + (((tl >> 3) ^ fr) & 7) * 8 + (tl & 7)] = w;
            }
            bar_lgkm();
            #pragma unroll
            for (int kc2 = 0; kc2 < 2; kc2++) {
                int o = fr * 64 + (((4 * kc2 + fq) ^ fr) & 7) * 8;
                short8v bd0 = *(const short8v*)&DTr[o];
                short8v bd1 = *(const short8v*)&DTr[1024 + o];
                #pragma unroll
                for (int dt = 0; dt < 4; dt++) {
                    short8v ak = *(const short8v*)&ba[SCKT + sw64b(64 * wv + 16 * dt + fr, 32 * kc2 + 8 * fq)];
                    sacc[dt] = __builtin_amdgcn_mfma_f32_16x16x32_bf16(ak, bd0, sacc[dt], 0, 0, 0);
                    sacc[dt] = __builtin_amdgcn_mfma_f32_16x16x32_bf16(ak, bd1, sacc[dt], 0, 0, 0);
                }
            }
        }
        return;
    }

    // ---------------- gemm part: Q [0,512) + G [2048,3072) ----------------
    {
        us* As = lds;            // [128][64]
        us* Bs = lds + 8192;     // [128][64]
        int wave = tid >> 6, lane = tid & 63;
        int wr = (wave >> 1) * 64, wc = (wave & 1) * 64;
        int fr = lane & 15, fq = lane >> 4;
        int wg = blockIdx.x - 128;            // 0..767
        wg = (wg & 7) * 96 + (wg >> 3);       // XCD swizzle (768 = 8*96)
        int m0 = (wg % 64) * 128;
        int ntile = wg / 64;                  // 0..11
        int n0 = ntile * 128 + (ntile >= 4 ? 1536 : 0);

        f32x4 acc[4][4];
        #pragma unroll
        for (int i = 0; i < 4; i++)
            #pragma unroll
            for (int j = 0; j < 4; j++) acc[i][j] = (f32x4){0.f, 0.f, 0.f, 0.f};

        int rl = lane >> 3, ul = lane & 7;

        for (int k0 = 0; k0 < DM; k0 += 64) {
            #pragma unroll
            for (int i = 0; i < 4; i++) {
                int row = wave * 32 + i * 8 + rl;
                GLDS16(&xb[(size_t)(m0 + row) * DM + k0 + ul * 8], As + (wave * 32 + i * 8) * 64);
                GLDS16(&WT[(size_t)(n0 + row) * DM + k0 + ul * 8], Bs + (wave * 32 + i * 8) * 64);
            }
            __syncthreads();
            #pragma unroll
            for (int kk = 0; kk < 2; kk++) {
                short8v a[4], b[4];
                #pragma unroll
                for (int i = 0; i < 4; i++) {
                    int ra = wr + i * 16 + fr;
                    a[i] = *(const short8v*)&As[ra * 64 + ((4 * kk + fq) ^ (ra & 7)) * 8];
                    int rb = wc + i * 16 + fr;
                    b[i] = *(const short8v*)&Bs[rb * 64 + ((4 * kk + fq) ^ (rb & 7)) * 8];
                }
                #pragma unroll
                for (int i = 0; i < 4; i++)
                    #pragma unroll
                    for (int j = 0; j < 4; j++)
                        acc[i][j] = __builtin_amdgcn_mfma_f32_16x16x32_bf16(a[i], b[j], acc[i][j], 0, 0, 0);
            }
            __syncthreads();
        }
        #pragma unroll
        for (int i = 0; i < 4; i++)
            #pragma unroll
            for (int j = 0; j < 4; j++)
                #pragma unroll
                for (int t = 0; t < 4; t++) {
                    int row = m0 + wr + i * 16 + fq * 4 + t;
                    int col = n0 + wc + j * 16 + fr;
                    QKVG[(size_t)row * NPROJ + col] = f2bf(acc[i][j][t]);
                }
    }
}

// ---------------- parallel output: P computed in-block; RACE-FREE layout ----------
#define K2_W 0        // 8192
#define K2_P 8192     // 4096
#define K2_U 12288    // 8192
#define K2_S 20480    // 16384
#define K2_Q 36864    // 8192
#define K2_DT 45056   // 8192 (j in [0,128))
#define K2_K 53248    // 8192
// total 61440 elems = 122880 B

__global__ __launch_bounds__(256, 1) void out_k(
    const us* __restrict__ QKVG, const us* __restrict__ Wbuf,
    const us* __restrict__ Ubuf, const us* __restrict__ Kbuf,
    const us* __restrict__ Sbuf, us* __restrict__ Ob)
{
    extern __shared__ us lds[];
    int tid = threadIdx.x;
    int wv = tid >> 6, ln = tid & 63;
    int fr = ln & 15, fq = ln >> 4;
    int c = blockIdx.x;
    int bh = blockIdx.y >> 1, jh = blockIdx.y & 1;
    int b = bh >> 2, h = bh & 3;
    int tok0 = b * SEQ + c * 64;
    size_t cb = (size_t)bh * NCHUNK + c;

    short8v id0, id1;
    #pragma unroll
    for (int e = 0; e < 8; e++) {
        id0[e] = (short)((8 * fq + e == fr) ? 0x3F80 : 0);
        id1[e] = (short)((8 * fq + e == fr + 16) ? 0x3F80 : 0);
    }

    #pragma unroll
    for (int i = 0; i < 4; i++) {
        int q = (i * 4 + wv) * 512 + ln * 8;
        GLDS16(Wbuf + cb * 8192 + q, lds + K2_W + (i * 4 + wv) * 512);
    }
    #pragma unroll
    for (int i = 0; i < 4; i++) {
        int q = (i * 4 + wv) * 512 + ln * 8;
        GLDS16(Kbuf + cb * 8192 + q, lds + K2_K + (i * 4 + wv) * 512);
    }
    #pragma unroll
    for (int i = 0; i < 4; i++) {
        int q = (i * 4 + wv) * 512 + ln * 8;
        int t = q >> 7, r = q & 127;
        GLDS16(Ubuf + cb * 16384 + t * 256 + jh * 128 + r, lds + K2_U + (i * 4 + wv) * 512);
    }
    size_t sbase = cb * 32768 + (size_t)jh * 16384;
    #pragma unroll
    for (int i = 0; i < 8; i++) {
        int q = (i * 4 + wv) * 512 + ln * 8;
        GLDS16(Sbuf + sbase + q, lds + K2_S + (i * 4 + wv) * 512);
    }
    short8v qv[4];
    #pragma unroll
    for (int i = 0; i < 4; i++) {
        int idx = tid + 256 * i;
        int t = idx >> 4, u = idx & 15;
        qv[i] = *(const short8v*)(QKVG + (size_t)(tok0 + t) * NPROJ + h * 128 + u * 8);
    }
    #pragma unroll
    for (int i = 0; i < 4; i++) {
        int idx = tid + 256 * i;
        int t = idx >> 4, u = idx & 15;
        *(short8v*)&lds[K2_Q + sw128(t, u * 8)] = qv[i];
    }
    __syncthreads();

    f32x4 dacc[8], oacc[8];
    #pragma unroll
    for (int jt = 0; jt < 8; jt++) {
        dacc[jt] = (f32x4){0.f, 0.f, 0.f, 0.f};
        oacc[jt] = (f32x4){0.f, 0.f, 0.f, 0.f};
    }
    #pragma unroll
    for (int ks = 0; ks < 4; ks++) {
        short8v aw = *(const short8v*)&lds[K2_W + (ks >> 1) * 4096
            + sw64(16 * wv + fr, (ks & 1) * 32 + 8 * fq)];
        short8v aq = *(const short8v*)&lds[K2_Q + sw128(16 * wv + fr, 32 * ks + 8 * fq)];
        #pragma unroll
        for (int jt = 0; jt < 8; jt++) {
            short8v bs = *(const short8v*)&lds[K2_S + jt * 2048 + (ks >> 1) * 1024
                + fr * 64 + ((((ks & 1) * 4 + fq) ^ fr) & 7) * 8];
            dacc[jt] = __builtin_amdgcn_mfma_f32_16x16x32_bf16(aw, bs, dacc[jt], 0, 0, 0);
            oacc[jt] = __builtin_amdgcn_mfma_f32_16x16x32_bf16(aq, bs, oacc[jt], 0, 0, 0);
        }
    }
    #pragma unroll
    for (int ju = 0; ju < 4; ju++) {
        short8v au = *(const short8v*)&lds[K2_U + swU128(16 * wv + fr, 32 * ju + 8 * fq)];
        dacc[2 * ju + 0] = __builtin_amdgcn_mfma_f32_16x16x32_bf16(au, id0, dacc[2 * ju + 0], 0, 0, 0);
        dacc[2 * ju + 1] = __builtin_amdgcn_mfma_f32_16x16x32_bf16(au, id1, dacc[2 * ju + 1], 0, 0, 0);
    }
    // P = SC * tril(Q K^T)
    {
        f32x4 pacc[4];
        #pragma unroll
        for (int jt2 = 0; jt2 < 4; jt2++) pacc[jt2] = (f32x4){0.f, 0.f, 0.f, 0.f};
        #pragma unroll
        for (int ks = 0; ks < 4; ks++) {
            short8v aq = *(const short8v*)&lds[K2_Q + sw128(16 * wv + fr, 32 * ks + 8 * fq)];
            #pragma unroll
            for (int jt2 = 0; jt2 < 4; jt2++) {
                short8v bk = *(const short8v*)&lds[K2_K + sw128(16 * jt2 + fr, 32 * ks + 8 * fq)];
                pacc[jt2] = __builtin_amdgcn_mfma_f32_16x16x32_bf16(aq, bk, pacc[jt2], 0, 0, 0);
            }
        }
        #pragma unroll
        for (int jt2 = 0; jt2 < 4; jt2++)
            #pragma unroll
            for (int r = 0; r < 4; r++) {
                int t = 16 * wv + 4 * fq + r, s = 16 * jt2 + fr;
                float val = (s <= t) ? pacc[jt2][r] * SCQ : 0.f;
                lds[K2_P + sw64(t, s)] = f2bf(val);
            }
    }
    #pragma unroll
    for (int jt = 0; jt < 8; jt++)
        #pragma unroll
        for (int r = 0; r < 4; r++) oacc[jt][r] *= SCQ;
    #pragma unroll
    for (int jt = 0; jt < 8; jt++) {
        int j = 16 * jt + fr;
        int t0 = 16 * wv + 4 * fq;
        uint2 w;
        w.x = cvtpk(dacc[jt][0], dacc[jt][1]);
        w.y = cvtpk(dacc[jt][2], dacc[jt][3]);
        *(uint2*)&lds[K2_DT + sw64(j, t0)] = w;
    }
    bar_lgkm();

    #pragma unroll
    for (int ks = 0; ks < 2; ks++) {
        short8v ap = *(const short8v*)&lds[K2_P + sw64(16 * wv + fr, 32 * ks + 8 * fq)];
        #pragma unroll
        for (int jt = 0; jt < 8; jt++) {
            short8v bd = *(const short8v*)&lds[K2_DT + sw64(16 * jt + fr, 32 * ks + 8 * fq)];
            oacc[jt] = __builtin_amdgcn_mfma_f32_16x16x32_bf16(ap, bd, oacc[jt], 0, 0, 0);
        }
    }
    us* ob = Ob + (size_t)tok0 * 1024 + h * 256 + jh * 128;
    #pragma unroll
    for (int jt = 0; jt < 8; jt++)
        #pragma unroll
        for (int r = 0; r < 4; r++) {
            int t = 16 * wv + 4 * fq + r;
            ob[(size_t)t * 1024 + 16 * jt + fr] = f2bf(oacc[jt][r]);
        }
}

// ---------------- RMSNorm + swish gate (writes o2 IMAGE for gemm1) ----------------
__global__ __launch_bounds__(256) void gate_norm(const us* __restrict__ Ob,
                                                 const us* __restrict__ QKVG,
                                                 const float* __restrict__ norm_w,
                                                 us* __restrict__ o2)
{
    int gid = blockIdx.x * 4 + (threadIdx.x >> 6);
    int ln = threadIdx.x & 63;
    int tok = gid >> 2, h = gid & 3;
    size_t base = (size_t)tok * 1024 + h * 256 + ln * 4;
    uint2 ov = *(const uint2*)&Ob[base];
    float o0 = bf2f((us)ov.x), o1 = bf2f((us)(ov.x >> 16));
    float o2v = bf2f((us)ov.y), o3 = bf2f((us)(ov.y >> 16));
    float ss = o0 * o0 + o1 * o1 + o2v * o2v + o3 * o3;
    #pragma unroll
    for (int off = 32; off; off >>= 1) ss += __shfl_xor(ss, off);
    float r = rsqrtf(ss * (1.0f / 256.0f) + 1e-5f);
    uint2 gv = *(const uint2*)&QKVG[(size_t)tok * NPROJ + 2048 + h * 256 + ln * 4];
    float g0 = bf2f((us)gv.x), g1 = bf2f((us)(gv.x >> 16));
    float g2 = bf2f((us)gv.y), g3 = bf2f((us)(gv.y >> 16));
    float4 nw = *(const float4*)&norm_w[ln * 4];
    float r0 = o0 * r * nw.x * (g0 / (1.f + __expf(-g0)));
    float r1 = o1 * r * nw.y * (g1 / (1.f + __expf(-g1)));
    float r2 = o2v * r * nw.z * (g2 / (1.f + __expf(-g2)));
    float r3 = o3 * r * nw.w * (g3 / (1.f + __expf(-g3)));
    uint2 w;
    w.x = cvtpk(r0, r1);
    w.y = cvtpk(r2, r3);
    int u = h * 32 + (ln >> 1);
    size_t dsto = (size_t)tok * 1024 + (size_t)(u >> 3) * 64
                + (size_t)(((u & 7) ^ (tok & 7)) * 8) + (ln & 1) * 4;
    *(uint2*)&o2[dsto] = w;
}

// ---------------- launch ----------------
extern "C" void kernel_launch(void* const* d_in, const int* in_sizes, int n_in,
                              void* d_out, int out_size, void* d_ws, size_t ws_size,
                              hipStream_t stream) {
    const float* x      = (const float*)d_in[0];
    const float* Wq     = (const float*)d_in[1];
    const float* Wk     = (const float*)d_in[2];
    const float* Wv     = (const float*)d_in[3];
    const float* Wb     = (const float*)d_in[4];
    const float* Wg     = (const float*)d_in[5];
    const float* Wo     = (const float*)d_in[6];
    const float* norm_w = (const float*)d_in[7];
    float* out = (float*)d_out;

    char* ws = (char*)d_ws;
    us*    xb   = (us*)(ws + 0);            // 16 MB
    us*    Ob   = (us*)(ws + 0);            // 16 MB (alias xb, dead after fused_scan_qg)
    us*    WT   = (us*)(ws + 16777216);     //  6 MB
    us*    KTbuf= (us*)(ws + 23068672);     //  8 MB
    us*    QKVG = (us*)(ws + 31457280);     // 48 MB
    float* beta = (float*)(ws + 81788928);  // 128 KB
    us*    Wbuf = (us*)(ws + 81920000);     //  8 MB
    us*    Ubuf = (us*)(ws + 90308608);     // 16 MB
    us*    o2   = (us*)(ws + 90308608);     // (alias Ubuf, dead after out_k)
    us*    Kbuf = (us*)(ws + 107085824);    //  8 MB
    us*    WoT  = (us*)(ws + 115474432);    //  2 MB
    us*    Sbuf = (us*)(ws + 117571584);    // 32 MB  (end ~144.1 MB)

    (void)hipFuncSetAttribute((const void*)fused_scan_qg,
                              hipFuncAttributeMaxDynamicSharedMemorySize, 81920);
    (void)hipFuncSetAttribute((const void*)out_k,
                              hipFuncAttributeMaxDynamicSharedMemorySize, 122880);

    // prep: convert+beta (4096 blocks) + 5 weight transposes (1024 blocks)
    prep<<<5120, 256, 0, stream>>>(x, xb, Wb, beta, Wq, Wk, Wv, Wg, Wo, WT, WoT);
    // K,V projection only (cols 512..2048)
    gemm_bt<0><<<dim3(64, 12), 256, 0, stream>>>(xb, WT + (size_t)512 * DM,
                                                 (void*)(QKVG + 512), NTOK, NPROJ, DM);
    chunk_pre<<<dim3(NCHUNK, 8), 256, 0, stream>>>(QKVG, beta, Wbuf, Ubuf, Kbuf, KTbuf);
    // scan (blocks 0..127) || Q,G projection (blocks 128..895)
    fused_scan_qg<<<896, 256, 81920, stream>>>(xb, WT, QKVG, Wbuf, Ubuf, KTbuf, Sbuf);
    out_k<<<dim3(NCHUNK, 16), 256, 122880, stream>>>(QKVG, Wbuf, Ubuf, Kbuf, Sbuf, Ob);
    gate_norm<<<NTOK, 256, 0, stream>>>(Ob, QKVG, norm_w, o2);
    gemm_bt<1><<<dim3(64, 8), 256, 0, stream>>>(o2, WoT, (void*)out, NTOK, DM, DM);
}

// Round 19
// 229.200 us; speedup vs baseline: 1.0216x; 1.0216x over previous
//
#include <hip/hip_runtime.h>
#include <hip/hip_bf16.h>
#include <stdint.h>
#include <stddef.h>

typedef __attribute__((ext_vector_type(8))) short short8v;   // 8 bf16 = 4 VGPR
typedef __attribute__((ext_vector_type(4))) float f32x4;
typedef unsigned short us;

__device__ __forceinline__ float bf2f(unsigned short u) {
    return __uint_as_float(((unsigned int)u) << 16);
}
__device__ __forceinline__ unsigned short f2bf(float f) {
    unsigned int x = __float_as_uint(f);
    x += 0x7fffu + ((x >> 16) & 1u);   // RNE
    return (unsigned short)(x >> 16);
}
__device__ __forceinline__ unsigned int cvtpk(float lo, float hi) {
    unsigned int r;
    asm("v_cvt_pk_bf16_f32 %0, %1, %2" : "=v"(r) : "v"(lo), "v"(hi));
    return r;
}

#define NTOK 8192
#define DM   1024
#define NPROJ 3072     // q512 | k512 | v1024 | g1024
#define SEQ  4096
#define NCHUNK 64
#define SCQ 0.08838834764831845f   // 128^-0.5

#define GLDS16(g, l) __builtin_amdgcn_global_load_lds( \
    (const __attribute__((address_space(1))) void*)(g), \
    (__attribute__((address_space(3))) void*)(l), 16, 0, 0)

__device__ __forceinline__ void bar_lgkm() {
    asm volatile("s_waitcnt lgkmcnt(0)" ::: "memory");
    __builtin_amdgcn_s_barrier();
    __builtin_amdgcn_sched_barrier(0);
}

// ---- swizzles (element offsets, 2B elems) ----
__device__ __forceinline__ int sw16(int row, int k) {
    int u = k >> 3;
    int us_ = (u & 8) | ((u ^ row) & 7);
    return row * 128 + us_ * 8 + (k & 7);
}
__device__ __forceinline__ int sw8(int row, int k) {
    int u = k >> 3;
    int us_ = (u ^ row) & 7;
    return row * 64 + us_ * 8 + (k & 7);
}
__device__ __forceinline__ int sw128(int row, int k) {   // [R][128] tile
    int u = k >> 3;
    return row * 128 + ((u ^ row) & 15) * 8 + (k & 7);
}
__device__ __forceinline__ int sw64(int row, int k) {    // [R][64] tile
    int u = k >> 3;
    return row * 64 + ((u ^ row) & 7) * 8 + (k & 7);
}
__device__ __forceinline__ int sw64b(int row, int k) {   // bank-spread scatter variant
    int u = k >> 3;
    return row * 64 + ((u ^ row ^ (row >> 3)) & 7) * 8 + (k & 7);
}
__device__ __forceinline__ int swU(int t, int j) {       // Ubuf [t][256]
    int jj = j & 127, u = jj >> 3;
    int us_ = (u & 8) | ((u ^ t) & 7);
    return t * 256 + (j >> 7) * 128 + us_ * 8 + (jj & 7);
}

// ---------------- PREP: x->bf16 image + beta (blocks 0..4095), W transposes (4096..5119) ----
__global__ __launch_bounds__(256) void prep(
    const float* __restrict__ x, us* __restrict__ xb,
    const float* __restrict__ Wb, float* __restrict__ beta,
    const float* __restrict__ Wq, const float* __restrict__ Wk,
    const float* __restrict__ Wv, const float* __restrict__ Wg,
    const float* __restrict__ Wo, us* __restrict__ WT, us* __restrict__ WoT)
{
    __shared__ float smem[64 * 65];
    int tid = threadIdx.x;
    int bid = blockIdx.x;

    if (bid < 4096) {
        int i = bid * 256 + tid;
        int tok = i >> 7;
        int kb = (i >> 3) & 15;
        int u = i & 7;
        int ko = kb * 64 + ((u ^ (tok & 7)) * 8);
        const float4* src = (const float4*)(x + (size_t)tok * 1024 + ko);
        float4 v0 = src[0], v1 = src[1];
        uint4 o;
        o.x = cvtpk(v0.x, v0.y); o.y = cvtpk(v0.z, v0.w);
        o.z = cvtpk(v1.x, v1.y); o.w = cvtpk(v1.z, v1.w);
        *(uint4*)(xb + (size_t)i * 8) = o;
        const float4* wbv = (const float4*)Wb;
        float xs[8] = {v0.x, v0.y, v0.z, v0.w, v1.x, v1.y, v1.z, v1.w};
        float4 s = {0.f, 0.f, 0.f, 0.f};
        #pragma unroll
        for (int e = 0; e < 8; e++) {
            float4 w = wbv[ko + e];
            s.x += xs[e] * w.x; s.y += xs[e] * w.y;
            s.z += xs[e] * w.z; s.w += xs[e] * w.w;
        }
        *(float4*)&smem[tid * 4] = s;
        __syncthreads();
        if (tid < 8) {
            int tp = tid >> 2, h = tid & 3;
            float acc = 0.f;
            for (int j = 0; j < 128; j++) acc += smem[(tp * 128 + j) * 4 + h];
            beta[(size_t)(bid * 2 + tp) * 4 + h] = 1.f / (1.f + __expf(-acc));
        }
        return;
    }

    int lb = bid - 4096;
    const float* srcw; us* dst; int N;
    if (lb < 128)      { srcw = Wq; dst = WT;                    N = 512;  }
    else if (lb < 256) { srcw = Wk; dst = WT + (size_t)512 * DM;  N = 512;  lb -= 128; }
    else if (lb < 512) { srcw = Wv; dst = WT + (size_t)1024 * DM; N = 1024; lb -= 256; }
    else if (lb < 768) { srcw = Wg; dst = WT + (size_t)2048 * DM; N = 1024; lb -= 512; }
    else               { srcw = Wo; dst = WoT;                   N = 1024; lb -= 768; }
    int nbx = N >> 6;
    int n0 = (lb % nbx) * 64, k0 = (lb / nbx) * 64;
    float (*tl)[65] = (float(*)[65])smem;
    int tr = tid >> 6, tc = tid & 63;
    #pragma unroll
    for (int i2 = 0; i2 < 16; i2++) {
        int kk = 4 * i2 + tr;
        tl[kk][tc] = srcw[(size_t)(k0 + kk) * N + n0 + tc];
    }
    __syncthreads();
    int n = tid >> 2, seg = (tid & 3) * 16;
    short8v a, b;
    #pragma unroll
    for (int e = 0; e < 8; e++) {
        a[e] = (short)f2bf(tl[seg + e][n]);
        b[e] = (short)f2bf(tl[seg + 8 + e][n]);
    }
    int n_ = n0 + n;
    int o1 = (tid & 3) * 2, o2_ = o1 + 1;
    us* d = dst + (size_t)n_ * DM + k0;
    *(short8v*)(d + (o1 ^ (n_ & 7)) * 8) = a;
    *(short8v*)(d + (o2_ ^ (n_ & 7)) * 8) = b;
}

// ---------------- bf16 MFMA GEMM, BK=64, image-swizzled, 2-phase dbuf -------
template<int OUT_F32>
__global__ __launch_bounds__(256) void gemm_bt(
    const us* __restrict__ A, const us* __restrict__ BT,
    void* __restrict__ C, int M, int N, int K)
{
    __shared__ us As[2][128 * 64];
    __shared__ us Bs[2][128 * 64];
    int tid = threadIdx.x;
    int wave = tid >> 6, lane = tid & 63;
    int wr = (wave >> 1) * 64, wc = (wave & 1) * 64;
    int fr = lane & 15, fq = lane >> 4;
    int nbx = gridDim.x, nwg = nbx * gridDim.y;
    int wg = blockIdx.y * nbx + blockIdx.x;
    int cpx = nwg >> 3;
    wg = (wg & 7) * cpx + (wg >> 3);
    int m0 = (wg % nbx) * 128, n0 = (wg / nbx) * 128;

    f32x4 acc[4][4];
    #pragma unroll
    for (int i = 0; i < 4; i++)
        #pragma unroll
        for (int j = 0; j < 4; j++) acc[i][j] = (f32x4){0.f, 0.f, 0.f, 0.f};

    int rl = lane >> 3, ul = lane & 7;

    auto issue = [&](int k0, int bufi) {
        #pragma unroll
        for (int i = 0; i < 4; i++) {
            int row = wave * 32 + i * 8 + rl;
            GLDS16(&A[(size_t)(m0 + row) * K + k0 + ul * 8], &As[bufi][(wave * 32 + i * 8) * 64]);
            GLDS16(&BT[(size_t)(n0 + row) * K + k0 + ul * 8], &Bs[bufi][(wave * 32 + i * 8) * 64]);
        }
    };

    int NT = K >> 6;
    issue(0, 0);
    if (NT > 1) issue(64, 1);

    for (int t = 0; t < NT; t++) {
        if (t + 1 < NT) asm volatile("s_waitcnt vmcnt(8)" ::: "memory");
        else            asm volatile("s_waitcnt vmcnt(0)" ::: "memory");
        __builtin_amdgcn_sched_barrier(0);
        __builtin_amdgcn_s_barrier();
        __builtin_amdgcn_sched_barrier(0);
        const us* as = As[t & 1];
        const us* bs = Bs[t & 1];
        #pragma unroll
        for (int kk = 0; kk < 2; kk++) {
            short8v a[4], b[4];
            #pragma unroll
            for (int i = 0; i < 4; i++) {
                int ra = wr + i * 16 + fr;
                a[i] = *(const short8v*)&as[ra * 64 + ((4 * kk + fq) ^ (ra & 7)) * 8];
                int rb = wc + i * 16 + fr;
                b[i] = *(const short8v*)&bs[rb * 64 + ((4 * kk + fq) ^ (rb & 7)) * 8];
            }
            #pragma unroll
            for (int i = 0; i < 4; i++)
                #pragma unroll
                for (int j = 0; j < 4; j++)
                    acc[i][j] = __builtin_amdgcn_mfma_f32_16x16x32_bf16(a[i], b[j], acc[i][j], 0, 0, 0);
        }
        bar_lgkm();
        if (t + 2 < NT) issue((t + 2) * 64, t & 1);
    }

    #pragma unroll
    for (int i = 0; i < 4; i++)
        #pragma unroll
        for (int j = 0; j < 4; j++)
            #pragma unroll
            for (int t = 0; t < 4; t++) {
                int row = m0 + wr + i * 16 + fq * 4 + t;
                int col = n0 + wc + j * 16 + fr;
                float val = acc[i][j][t];
                if (OUT_F32) ((float*)C)[(size_t)row * N + col] = val;
                else ((us*)C)[(size_t)row * N + col] = f2bf(val);
            }
}

// ---------------- per-chunk precompute (NO Q dependency; writes Kbuf image) -------
__global__ __launch_bounds__(256) void chunk_pre(
    const us* __restrict__ QKVG, const float* __restrict__ beta,
    us* __restrict__ Wbuf, us* __restrict__ Ubuf,
    us* __restrict__ Kbuf, us* __restrict__ KTbuf)
{
    __shared__ us Ks[8192];
    __shared__ us KTs[8192];
    __shared__ us VT[8192];
    __shared__ us Tb[4096];
    __shared__ float Af[64][64];
    __shared__ float betas[64];

    int c = blockIdx.x, bh = blockIdx.y;
    int b = bh >> 2, h = bh & 3;
    int tid = threadIdx.x;
    int wv = tid >> 6, ln = tid & 63;
    int fr = ln & 15, fq = ln >> 4;
    int tok0 = b * SEQ + c * 64;
    size_t cb = (size_t)bh * NCHUNK + c;

    #pragma unroll
    for (int r = 0; r < 4; r++) {
        int idx = tid + 256 * r;
        int t = idx >> 4, u = idx & 15;
        short8v kv = *(const short8v*)(QKVG + (size_t)(tok0 + t) * NPROJ + 512 + h * 128 + u * 8);
        *(short8v*)(Ks + sw16(t, u * 8)) = kv;
    }
    if (tid < 64) betas[tid] = beta[(size_t)(tok0 + tid) * 4 + h];
    __syncthreads();

    {   // L2-normalize K rows
        int t = tid >> 2, p = tid & 3;
        short8v v[4];
        float ss = 0.f;
        #pragma unroll
        for (int uu = 0; uu < 4; uu++) {
            v[uu] = *(const short8v*)(Ks + sw16(t, (p * 4 + uu) * 8));
            #pragma unroll
            for (int e = 0; e < 8; e++) {
                float f = bf2f((unsigned short)v[uu][e]);
                ss += f * f;
            }
        }
        ss += __shfl_xor(ss, 1);
        ss += __shfl_xor(ss, 2);
        float rn = rsqrtf(ss + 1e-12f);
        #pragma unroll
        for (int uu = 0; uu < 4; uu++) {
            short8v o;
            #pragma unroll
            for (int e = 0; e < 8; e++)
                o[e] = (short)f2bf(bf2f((unsigned short)v[uu][e]) * rn);
            *(short8v*)(Ks + sw16(t, (p * 4 + uu) * 8)) = o;
        }
    }
    __syncthreads();

    {   // A = strict_tril(beta_t K K^T)
        f32x4 aacc[4];
        #pragma unroll
        for (int jt = 0; jt < 4; jt++) aacc[jt] = (f32x4){0.f, 0.f, 0.f, 0.f};
        #pragma unroll
        for (int ks = 0; ks < 4; ks++) {
            short8v ak = *(const short8v*)(Ks + sw16(16 * wv + fr, 32 * ks + 8 * fq));
            #pragma unroll
            for (int jt = 0; jt < 4; jt++) {
                short8v bk = *(const short8v*)(Ks + sw16(16 * jt + fr, 32 * ks + 8 * fq));
                aacc[jt] = __builtin_amdgcn_mfma_f32_16x16x32_bf16(ak, bk, aacc[jt], 0, 0, 0);
            }
        }
        #pragma unroll
        for (int jt = 0; jt < 4; jt++)
            #pragma unroll
            for (int r = 0; r < 4; r++) {
                int t = 16 * wv + 4 * fq + r, s = 16 * jt + fr;
                if (s < t) Af[t][s] = betas[t] * aacc[jt][r];
            }
    }
    __syncthreads();

    if (wv == 0) {
        int cc = ln;
        for (int tb = 0; tb < 8; tb++) {
            int base = tb * 8;
            float xs[8];
            #pragma unroll
            for (int i = 0; i < 8; i++) {
                int t = base + i;
                float v = Af[t][cc];
                #pragma unroll
                for (int s = 0; s < i; s++)
                    v += Af[t][base + s] * xs[s];
                float xt = (cc < t) ? -v : 0.f;
                xs[i] = xt;
                if (cc < t) Af[t][cc] = xt;
            }
            for (int r = base + 8; r < 64; r += 2) {
                float u0 = 0.f, u1 = 0.f;
                #pragma unroll
                for (int s = 0; s < 8; s++) {
                    float a0 = Af[r][base + s];
                    float a1 = Af[r + 1][base + s];
                    u0 += a0 * xs[s];
                    u1 += a1 * xs[s];
                }
                Af[r][cc] += u0;
                Af[r + 1][cc] += u1;
            }
        }
    } else {
        int q = tid - 64;
        for (int g = q; g < 1024; g += 192) {
            int t = g >> 4, u = g & 15;
            short8v kv = *(const short8v*)(Ks + sw16(t, u * 8));
            #pragma unroll
            for (int e = 0; e < 8; e++)
                KTs[sw64b(u * 8 + e, t)] = (unsigned short)kv[e];
        }
        for (int g = q; g < 1024; g += 192) {
            int t = g >> 4, jg = g & 15;
            short8v vv = *(const short8v*)(QKVG + (size_t)(tok0 + t) * NPROJ + 1024 + h * 256 + jg * 8);
            #pragma unroll
            for (int e = 0; e < 8; e++)
                VT[sw64b(jg * 8 + e, t)] = (unsigned short)vv[e];
        }
    }
    __syncthreads();

    {   // Kbuf image (normalized K, sw128), Tb, KTbuf image copy
        #pragma unroll
        for (int i = 0; i < 4; i++) {
            int idx = tid + 256 * i;
            int t = idx >> 4, u = idx & 15;
            short8v kv = *(const short8v*)(Ks + sw16(t, u * 8));
            *(short8v*)(Kbuf + cb * 8192 + t * 128 + (size_t)(((u ^ t) & 15) * 8)) = kv;
        }
        #pragma unroll
        for (int i = 0; i < 16; i++) {
            int idx = tid + 256 * i;
            int t = idx >> 6, s = idx & 63;
            float tv = (s < t) ? Af[t][s] : (s == t ? 1.f : 0.f);
            Tb[sw8(t, s)] = f2bf(tv * betas[s]);
        }
        #pragma unroll
        for (int i = 0; i < 4; i++) {
            int idx = tid + 256 * i;
            *(short8v*)(KTbuf + cb * 8192 + (size_t)idx * 8) =
                *(const short8v*)(KTs + (size_t)idx * 8);
        }
    }
    __syncthreads();

    {   // W = -(T'K) (d-half images), U half0
        f32x4 wacc[8], uacc[8];
        #pragma unroll
        for (int jt = 0; jt < 8; jt++) {
            wacc[jt] = (f32x4){0.f, 0.f, 0.f, 0.f};
            uacc[jt] = (f32x4){0.f, 0.f, 0.f, 0.f};
        }
        #pragma unroll
        for (int ks = 0; ks < 2; ks++) {
            short8v at = *(const short8v*)(Tb + sw8(16 * wv + fr, 32 * ks + 8 * fq));
            #pragma unroll
            for (int jt = 0; jt < 8; jt++) {
                short8v bk = *(const short8v*)(KTs + sw64b(16 * jt + fr, 32 * ks + 8 * fq));
                wacc[jt] = __builtin_amdgcn_mfma_f32_16x16x32_bf16(at, bk, wacc[jt], 0, 0, 0);
                short8v bv = *(const short8v*)(VT + sw64b(16 * jt + fr, 32 * ks + 8 * fq));
                uacc[jt] = __builtin_amdgcn_mfma_f32_16x16x32_bf16(at, bv, uacc[jt], 0, 0, 0);
            }
        }
        #pragma unroll
        for (int jt = 0; jt < 8; jt++)
            #pragma unroll
            for (int r = 0; r < 4; r++) {
                int t = 16 * wv + 4 * fq + r, d = 16 * jt + fr;
                Wbuf[cb * 8192 + (d >> 6) * 4096 + sw64(t, d & 63)] = f2bf(-wacc[jt][r]);
                Ubuf[cb * 16384 + swU(t, d)] = f2bf(uacc[jt][r]);
            }
    }
    __syncthreads();

    #pragma unroll
    for (int i = 0; i < 4; i++) {   // restage V^T half1
        int g = tid + 256 * i;
        int t = g >> 4, jg = g & 15;
        short8v vv = *(const short8v*)(QKVG + (size_t)(tok0 + t) * NPROJ + 1024 + h * 256 + 128 + jg * 8);
        #pragma unroll
        for (int e = 0; e < 8; e++)
            VT[sw64b(jg * 8 + e, t)] = (unsigned short)vv[e];
    }
    __syncthreads();
    {
        f32x4 uacc[8];
        #pragma unroll
        for (int jt = 0; jt < 8; jt++) uacc[jt] = (f32x4){0.f, 0.f, 0.f, 0.f};
        #pragma unroll
        for (int ks = 0; ks < 2; ks++) {
            short8v at = *(const short8v*)(Tb + sw8(16 * wv + fr, 32 * ks + 8 * fq));
            #pragma unroll
            for (int jt = 0; jt < 8; jt++) {
                short8v bv = *(const short8v*)(VT + sw64b(16 * jt + fr, 32 * ks + 8 * fq));
                uacc[jt] = __builtin_amdgcn_mfma_f32_16x16x32_bf16(at, bv, uacc[jt], 0, 0, 0);
            }
        }
        #pragma unroll
        for (int jt = 0; jt < 8; jt++)
            #pragma unroll
            for (int r = 0; r < 4; r++) {
                int t = 16 * wv + 4 * fq + r, j = 16 * jt + fr;
                Ubuf[cb * 16384 + swU(t, 128 + j)] = f2bf(uacc[jt][r]);
            }
    }
}

// ---------------- FUSED: serial scan (blocks 0..127) + Q/G projection gemm ----------
#define SCW 0
#define SCKT 8192
#define SCU 16384
#define SCBUF 17408
#define SSTB (2 * SCBUF)
#define SDTB (2 * SCBUF + 2048)

__global__ __launch_bounds__(256, 1) void fused_scan_qg(
    const us* __restrict__ xb, const us* __restrict__ WT, us* __restrict__ QKVG,
    const us* __restrict__ Wbuf, const us* __restrict__ Ubuf,
    const us* __restrict__ KTbuf, us* __restrict__ Sbuf)
{
    extern __shared__ us lds[];
    int tid = threadIdx.x;

    if (blockIdx.x < 128) {
        if (tid >= 128) {
            for (int c = 0; c < NCHUNK; c++) __builtin_amdgcn_s_barrier();
            return;
        }
        int wv = tid >> 6, ln = tid & 63;
        int fr = ln & 15, fq = ln >> 4;
        int sl = blockIdx.x >> 3;
        int j0 = sl * 16;
        int bh = blockIdx.x & 7;

        short8v id0;
        #pragma unroll
        for (int e = 0; e < 8; e++)
            id0[e] = (short)((8 * fq + e == fr) ? 0x3F80 : 0);

        f32x4 sacc[4];
        #pragma unroll
        for (int i = 0; i < 4; i++) sacc[i] = (f32x4){0.f, 0.f, 0.f, 0.f};

        us* ST = lds + SSTB + wv * 1024;

        auto issue = [&](int c1) {
            size_t cb = (size_t)bh * NCHUNK + c1;
            us* dst = lds + (c1 & 1) * SCBUF;
            const us* Wc = Wbuf + cb * 8192 + wv * 4096;
            const us* Kc = KTbuf + cb * 8192 + wv * 4096;
            #pragma unroll
            for (int i = 0; i < 8; i++) {
                GLDS16(Wc + i * 512 + ln * 8, dst + SCW + wv * 4096 + i * 512);
                GLDS16(Kc + i * 512 + ln * 8, dst + SCKT + wv * 4096 + i * 512);
            }
            if (wv) {
                const us* Uc = Ubuf + cb * 16384;
                #pragma unroll
                for (int i = 0; i < 2; i++) {
                    int t = i * 32 + (ln >> 1);
                    GLDS16(Uc + swU(t, j0 + (ln & 1) * 8), dst + SCU + i * 512);
                }
            }
        };

        issue(0);

        for (int c = 0; c < NCHUNK; c++) {
            const us* ba = lds + (c & 1) * SCBUF;
            us* DTw = lds + SDTB + (c & 1) * 2048 + wv * 1024;
            const us* DTr = lds + SDTB + (c & 1) * 2048;
            size_t sb = ((size_t)bh * NCHUNK + c) * 32768 + sl * 2048 + wv * 1024;

            #pragma unroll
            for (int dt = 0; dt < 4; dt++) {
                uint2 w;
                w.x = cvtpk(sacc[dt][0], sacc[dt][1]);
                w.y = cvtpk(sacc[dt][2], sacc[dt][3]);
                int dl = 16 * dt + 4 * fq;
                int off = fr * 64 + (((dl >> 3) ^ fr) & 7) * 8 + (dl & 7);
                *(uint2*)&ST[off] = w;
                *(uint2*)(Sbuf + sb + off) = w;
            }
            if (c + 1 < NCHUNK) issue(c + 1);
            if (c + 1 < NCHUNK) {
                if (wv) asm volatile("s_waitcnt vmcnt(22)" ::: "memory");
                else    asm volatile("s_waitcnt vmcnt(20)" ::: "memory");
            } else {
                asm volatile("s_waitcnt vmcnt(4)" ::: "memory");
            }
            __builtin_amdgcn_sched_barrier(0);

            f32x4 dacc[4];
            #pragma unroll
            for (int tt = 0; tt < 4; tt++) dacc[tt] = (f32x4){0.f, 0.f, 0.f, 0.f};
            #pragma unroll
            for (int kc = 0; kc < 2; kc++) {
                short8v bs = *(const short8v*)&ST[fr * 64 + (((4 * kc + fq) ^ fr) & 7) * 8];
                #pragma unroll
                for (int tt = 0; tt < 4; tt++) {
                    short8v aw = *(const short8v*)&ba[SCW + wv * 4096 + sw64(16 * tt + fr, 32 * kc + 8 * fq)];
                    dacc[tt] = __builtin_amdgcn_mfma_f32_16x16x32_bf16(aw, bs, dacc[tt], 0, 0, 0);
                }
            }
            if (wv) {
                #pragma unroll
                for (int tt = 0; tt < 4; tt++) {
                    short8v au = *(const short8v*)&ba[SCU + (16 * tt + fr) * 16 + 8 * (fq & 1)];
                    dacc[tt] = __builtin_amdgcn_mfma_f32_16x16x32_bf16(au, id0, dacc[tt], 0, 0, 0);
                }
            }
            #pragma unroll
            for (int tt = 0; tt < 4; tt++) {
                uint2 w;
                w.x = cvtpk(dacc[tt][0], dacc[tt][1]);
                w.y = cvtpk(dacc[tt][2], dacc[tt][3]);
                int tl = 16 * tt + 4 * fq;
                *(uint2*)&DTw[fr * 64 + (((tl >> 3) ^ fr) & 7) * 8 + (tl & 7)] = w;
            }
            bar_lgkm();
            #pragma unroll
            for (int kc2 = 0; kc2 < 2; kc2++) {
                int o = fr * 64 + (((4 * kc2 + fq) ^ fr) & 7) * 8;
                short8v bd0 = *(const short8v*)&DTr[o];
                short8v bd1 = *(const short8v*)&DTr[1024 + o];
                #pragma unroll
                for (int dt = 0; dt < 4; dt++) {
                    short8v ak = *(const short8v*)&ba[SCKT + sw64b(64 * wv + 16 * dt + fr, 32 * kc2 + 8 * fq)];
                    sacc[dt] = __builtin_amdgcn_mfma_f32_16x16x32_bf16(ak, bd0, sacc[dt], 0, 0, 0);
                    sacc[dt] = __builtin_amdgcn_mfma_f32_16x16x32_bf16(ak, bd1, sacc[dt], 0, 0, 0);
                }
            }
        }
        return;
    }

    // ---------------- gemm part: Q [0,512) + G [2048,3072) ----------------
    {
        us* As = lds;
        us* Bs = lds + 8192;
        int wave = tid >> 6, lane = tid & 63;
        int wr = (wave >> 1) * 64, wc = (wave & 1) * 64;
        int fr = lane & 15, fq = lane >> 4;
        int wg = blockIdx.x - 128;
        wg = (wg & 7) * 96 + (wg >> 3);
        int m0 = (wg % 64) * 128;
        int ntile = wg / 64;
        int n0 = ntile * 128 + (ntile >= 4 ? 1536 : 0);

        f32x4 acc[4][4];
        #pragma unroll
        for (int i = 0; i < 4; i++)
            #pragma unroll
            for (int j = 0; j < 4; j++) acc[i][j] = (f32x4){0.f, 0.f, 0.f, 0.f};

        int rl = lane >> 3, ul = lane & 7;

        for (int k0 = 0; k0 < DM; k0 += 64) {
            #pragma unroll
            for (int i = 0; i < 4; i++) {
                int row = wave * 32 + i * 8 + rl;
                GLDS16(&xb[(size_t)(m0 + row) * DM + k0 + ul * 8], As + (wave * 32 + i * 8) * 64);
                GLDS16(&WT[(size_t)(n0 + row) * DM + k0 + ul * 8], Bs + (wave * 32 + i * 8) * 64);
            }
            __syncthreads();
            #pragma unroll
            for (int kk = 0; kk < 2; kk++) {
                short8v a[4], b[4];
                #pragma unroll
                for (int i = 0; i < 4; i++) {
                    int ra = wr + i * 16 + fr;
                    a[i] = *(const short8v*)&As[ra * 64 + ((4 * kk + fq) ^ (ra & 7)) * 8];
                    int rb = wc + i * 16 + fr;
                    b[i] = *(const short8v*)&Bs[rb * 64 + ((4 * kk + fq) ^ (rb & 7)) * 8];
                }
                #pragma unroll
                for (int i = 0; i < 4; i++)
                    #pragma unroll
                    for (int j = 0; j < 4; j++)
                        acc[i][j] = __builtin_amdgcn_mfma_f32_16x16x32_bf16(a[i], b[j], acc[i][j], 0, 0, 0);
            }
            __syncthreads();
        }
        #pragma unroll
        for (int i = 0; i < 4; i++)
            #pragma unroll
            for (int j = 0; j < 4; j++)
                #pragma unroll
                for (int t = 0; t < 4; t++) {
                    int row = m0 + wr + i * 16 + fq * 4 + t;
                    int col = n0 + wc + j * 16 + fr;
                    QKVG[(size_t)row * NPROJ + col] = f2bf(acc[i][j][t]);
                }
    }
}

// ---------------- out_k + gate_norm fused: 512 threads, both jh halves ----------------
// LDS elems: W [0,8192) | K [8192,16384) | P [16384,20480) | S [20480,53248) | DT [53248,69632)
// epilogue reuse: OS f32 (64 x 260) over [0,33280); G (64x256 bf16) over DT region.
#define OKW 0
#define OKK 8192
#define OKP 16384
#define OKS 20480
#define OKDT 53248
// total 69632 elems = 139264 B

__global__ __launch_bounds__(512, 1) void out_k(
    const us* __restrict__ QKVG, const us* __restrict__ Wbuf,
    const us* __restrict__ Ubuf, const us* __restrict__ Kbuf,
    const us* __restrict__ Sbuf, const float* __restrict__ norm_w,
    us* __restrict__ o2)
{
    extern __shared__ us lds[];
    int tid = threadIdx.x;
    int wvg = (tid >> 6) & 3;   // wave within group
    int jh = tid >> 8;          // group: j-half
    int ln = tid & 63;
    int fr = ln & 15, fq = ln >> 4;
    int c = blockIdx.x;
    int bh = blockIdx.y;
    int b = bh >> 2, h = bh & 3;
    int tok0 = b * SEQ + c * 64;
    size_t cb = (size_t)bh * NCHUNK + c;

    short8v id0, id1;
    #pragma unroll
    for (int e = 0; e < 8; e++) {
        id0[e] = (short)((8 * fq + e == fr) ? 0x3F80 : 0);
        id1[e] = (short)((8 * fq + e == fr + 16) ? 0x3F80 : 0);
    }

    // stage W, K (2 loads/thread each), S (8 loads/thread)
    #pragma unroll
    for (int i = 0; i < 2; i++) {
        int q = (tid + 512 * i) * 8;
        GLDS16(Wbuf + cb * 8192 + q, lds + OKW + q);
        GLDS16(Kbuf + cb * 8192 + q, lds + OKK + q);
    }
    #pragma unroll
    for (int i = 0; i < 8; i++) {
        int q = (tid + 512 * i) * 8;
        GLDS16(Sbuf + cb * 32768 + q, lds + OKS + q);
    }
    // Q A-fragments: per-lane global loads
    short8v qf[4];
    #pragma unroll
    for (int ks = 0; ks < 4; ks++)
        qf[ks] = *(const short8v*)(QKVG + (size_t)(tok0 + 16 * wvg + fr) * NPROJ
                                   + h * 128 + ks * 32 + fq * 8);
    __syncthreads();

    f32x4 dacc[8], oacc[8];
    #pragma unroll
    for (int jt = 0; jt < 8; jt++) {
        dacc[jt] = (f32x4){0.f, 0.f, 0.f, 0.f};
        oacc[jt] = (f32x4){0.f, 0.f, 0.f, 0.f};
    }
    #pragma unroll
    for (int ks = 0; ks < 4; ks++) {
        short8v aw = *(const short8v*)&lds[OKW + (ks >> 1) * 4096
            + sw64(16 * wvg + fr, (ks & 1) * 32 + 8 * fq)];
        short8v aq = qf[ks];
        #pragma unroll
        for (int jt = 0; jt < 8; jt++) {
            short8v bs = *(const short8v*)&lds[OKS + jh * 16384 + jt * 2048 + (ks >> 1) * 1024
                + fr * 64 + ((((ks & 1) * 4 + fq) ^ fr) & 7) * 8];
            dacc[jt] = __builtin_amdgcn_mfma_f32_16x16x32_bf16(aw, bs, dacc[jt], 0, 0, 0);
            oacc[jt] = __builtin_amdgcn_mfma_f32_16x16x32_bf16(aq, bs, oacc[jt], 0, 0, 0);
        }
    }
    // U injection: per-lane global A-fragments
    #pragma unroll
    for (int ju = 0; ju < 4; ju++) {
        short8v au = *(const short8v*)(Ubuf + cb * 16384
            + swU(16 * wvg + fr, jh * 128 + 32 * ju + 8 * fq));
        dacc[2 * ju + 0] = __builtin_amdgcn_mfma_f32_16x16x32_bf16(au, id0, dacc[2 * ju + 0], 0, 0, 0);
        dacc[2 * ju + 1] = __builtin_amdgcn_mfma_f32_16x16x32_bf16(au, id1, dacc[2 * ju + 1], 0, 0, 0);
    }
    // P = SC * tril(Q K^T): group 0 only
    if (jh == 0) {
        f32x4 pacc[4];
        #pragma unroll
        for (int jt2 = 0; jt2 < 4; jt2++) pacc[jt2] = (f32x4){0.f, 0.f, 0.f, 0.f};
        #pragma unroll
        for (int ks = 0; ks < 4; ks++) {
            short8v aq = qf[ks];
            #pragma unroll
            for (int jt2 = 0; jt2 < 4; jt2++) {
                short8v bk = *(const short8v*)&lds[OKK + sw128(16 * jt2 + fr, 32 * ks + 8 * fq)];
                pacc[jt2] = __builtin_amdgcn_mfma_f32_16x16x32_bf16(aq, bk, pacc[jt2], 0, 0, 0);
            }
        }
        #pragma unroll
        for (int jt2 = 0; jt2 < 4; jt2++)
            #pragma unroll
            for (int r = 0; r < 4; r++) {
                int t = 16 * wvg + 4 * fq + r, s = 16 * jt2 + fr;
                float val = (s <= t) ? pacc[jt2][r] * SCQ : 0.f;
                lds[OKP + sw64(t, s)] = f2bf(val);
            }
    }
    #pragma unroll
    for (int jt = 0; jt < 8; jt++)
        #pragma unroll
        for (int r = 0; r < 4; r++) oacc[jt][r] *= SCQ;
    // Delta^T -> DT (full 256-row tile)
    #pragma unroll
    for (int jt = 0; jt < 8; jt++) {
        int jg = jh * 128 + 16 * jt + fr;
        int t0 = 16 * wvg + 4 * fq;
        uint2 w;
        w.x = cvtpk(dacc[jt][0], dacc[jt][1]);
        w.y = cvtpk(dacc[jt][2], dacc[jt][3]);
        *(uint2*)&lds[OKDT + sw64(jg, t0)] = w;
    }
    bar_lgkm();

    // oacc += P * Delta
    #pragma unroll
    for (int ks = 0; ks < 2; ks++) {
        short8v ap = *(const short8v*)&lds[OKP + sw64(16 * wvg + fr, 32 * ks + 8 * fq)];
        #pragma unroll
        for (int jt = 0; jt < 8; jt++) {
            short8v bd = *(const short8v*)&lds[OKDT + sw64(jh * 128 + 16 * jt + fr, 32 * ks + 8 * fq)];
            oacc[jt] = __builtin_amdgcn_mfma_f32_16x16x32_bf16(ap, bd, oacc[jt], 0, 0, 0);
        }
    }
    __syncthreads();   // everyone done reading P/S/DT

    // epilogue: O -> f32 LDS (stride 260); stage G over dead DT region
    float* OSf = (float*)lds;
    #pragma unroll
    for (int jt = 0; jt < 8; jt++)
        #pragma unroll
        for (int r = 0; r < 4; r++) {
            int t = 16 * wvg + 4 * fq + r;
            OSf[t * 260 + jh * 128 + 16 * jt + fr] = oacc[jt][r];
        }
    #pragma unroll
    for (int l = 0; l < 4; l++) {
        int idx = tid + 512 * l;            // 0..2047
        int tt = idx >> 5, ccol = (idx & 31) * 8;
        GLDS16(QKVG + (size_t)(tok0 + tt) * NPROJ + 2048 + h * 256 + ccol,
               lds + OKDT + idx * 8);
    }
    __syncthreads();   // drains vmcnt (gload_lds) + lds writes

    // RMSNorm + swish gate; write o2 image. 8 threads per row t.
    {
        int t = tid >> 3, p = tid & 7;
        int tok = tok0 + t;
        f32x4 ov[8];
        float ssum = 0.f;
        #pragma unroll
        for (int g = 0; g < 8; g++) {
            ov[g] = *(const f32x4*)&OSf[t * 260 + 32 * p + 4 * g];
            ssum += ov[g][0] * ov[g][0] + ov[g][1] * ov[g][1]
                  + ov[g][2] * ov[g][2] + ov[g][3] * ov[g][3];
        }
        ssum += __shfl_xor(ssum, 1);
        ssum += __shfl_xor(ssum, 2);
        ssum += __shfl_xor(ssum, 4);
        float rr = rsqrtf(ssum * (1.0f / 256.0f) + 1e-5f);
        #pragma unroll
        for (int g = 0; g < 8; g++) {
            int j0g = 32 * p + 4 * g;
            uint2 gv = *(const uint2*)&lds[OKDT + t * 256 + j0g];
            float4 nw = *(const float4*)&norm_w[j0g];
            float g0 = bf2f((us)gv.x), g1 = bf2f((us)(gv.x >> 16));
            float g2 = bf2f((us)gv.y), g3 = bf2f((us)(gv.y >> 16));
            float r0 = ov[g][0] * rr * nw.x * (g0 / (1.f + __expf(-g0)));
            float r1 = ov[g][1] * rr * nw.y * (g1 / (1.f + __expf(-g1)));
            float r2 = ov[g][2] * rr * nw.z * (g2 / (1.f + __expf(-g2)));
            float r3 = ov[g][3] * rr * nw.w * (g3 / (1.f + __expf(-g3)));
            uint2 w;
            w.x = cvtpk(r0, r1);
            w.y = cvtpk(r2, r3);
            int u = h * 32 + (j0g >> 3);
            size_t dsto = (size_t)tok * 1024 + (size_t)(u >> 3) * 64
                        + (size_t)(((u & 7) ^ (tok & 7)) * 8) + (j0g & 7);
            *(uint2*)&o2[dsto] = w;
        }
    }
}

// ---------------- launch ----------------
extern "C" void kernel_launch(void* const* d_in, const int* in_sizes, int n_in,
                              void* d_out, int out_size, void* d_ws, size_t ws_size,
                              hipStream_t stream) {
    const float* x      = (const float*)d_in[0];
    const float* Wq     = (const float*)d_in[1];
    const float* Wk     = (const float*)d_in[2];
    const float* Wv     = (const float*)d_in[3];
    const float* Wb     = (const float*)d_in[4];
    const float* Wg     = (const float*)d_in[5];
    const float* Wo     = (const float*)d_in[6];
    const float* norm_w = (const float*)d_in[7];
    float* out = (float*)d_out;

    char* ws = (char*)d_ws;
    us*    xb   = (us*)(ws + 0);            // 16 MB
    us*    o2   = (us*)(ws + 0);            // 16 MB (alias xb, dead after fused_scan_qg)
    us*    WT   = (us*)(ws + 16777216);     //  6 MB
    us*    KTbuf= (us*)(ws + 23068672);     //  8 MB
    us*    QKVG = (us*)(ws + 31457280);     // 48 MB
    float* beta = (float*)(ws + 81788928);  // 128 KB
    us*    Wbuf = (us*)(ws + 81920000);     //  8 MB
    us*    Ubuf = (us*)(ws + 90308608);     // 16 MB
    us*    Kbuf = (us*)(ws + 107085824);    //  8 MB
    us*    WoT  = (us*)(ws + 115474432);    //  2 MB
    us*    Sbuf = (us*)(ws + 117571584);    // 32 MB  (end ~144.1 MB)

    (void)hipFuncSetAttribute((const void*)fused_scan_qg,
                              hipFuncAttributeMaxDynamicSharedMemorySize, 81920);
    (void)hipFuncSetAttribute((const void*)out_k,
                              hipFuncAttributeMaxDynamicSharedMemorySize, 139264);

    // prep: convert+beta (4096 blocks) + 5 weight transposes (1024 blocks)
    prep<<<5120, 256, 0, stream>>>(x, xb, Wb, beta, Wq, Wk, Wv, Wg, Wo, WT, WoT);
    // K,V projection only (cols 512..2048)
    gemm_bt<0><<<dim3(64, 12), 256, 0, stream>>>(xb, WT + (size_t)512 * DM,
                                                 (void*)(QKVG + 512), NTOK, NPROJ, DM);
    chunk_pre<<<dim3(NCHUNK, 8), 256, 0, stream>>>(QKVG, beta, Wbuf, Ubuf, Kbuf, KTbuf);
    // scan (blocks 0..127) || Q,G projection (blocks 128..895)
    fused_scan_qg<<<896, 256, 81920, stream>>>(xb, WT, QKVG, Wbuf, Ubuf, KTbuf, Sbuf);
    // out + RMSNorm + swish gate fused (writes o2 image directly)
    out_k<<<dim3(NCHUNK, 8), 512, 139264, stream>>>(QKVG, Wbuf, Ubuf, Kbuf, Sbuf, norm_w, o2);
    gemm_bt<1><<<dim3(64, 8), 256, 0, stream>>>(o2, WoT, (void*)out, NTOK, DM, DM);
}